// Round 1
// baseline (3345.358 us; speedup 1.0000x reference)
//
#include <hip/hip_runtime.h>

#define LRELU_SLOPE 0.01f
#define NEG_BIG -1e10f

static __device__ __forceinline__ float lrelu_f(float x) {
    return x >= 0.0f ? x : LRELU_SLOPE * x;
}

constexpr int BM = 64, BN = 64, BK = 16;

// Generic tiled fp32 GEMM: C[m,n] = epilogue( sum_k A(m,k) * B(k,n) )
//  TRANS_A: A stored K-major (element (m,k) at A[k*lda + m]) -- used for o2^T @ r1m
//  TRANS_B: B stored N-major (element (k,n) at B[n*ldb + k]) -- used for r1m @ r2m^T
//  Concat A: for k < Ksplit read A0, else A1 at (k - Ksplit). Pass Ksplit=K to disable.
//  Epilogues: +bias[n], LeakyReLU, *rowmask, pairwise additive -1e10 mask.
template<bool TRANS_A, bool TRANS_B, bool BIAS, bool DO_LRELU, bool ROWMASK, bool PAIRMASK>
__global__ __launch_bounds__(256)
void gemm_kernel(const float* __restrict__ A0, const float* __restrict__ A1,
                 const float* __restrict__ B, const float* __restrict__ bias,
                 const int* __restrict__ rm1, const int* __restrict__ rm2,
                 float* __restrict__ C,
                 int M, int N, int K, int Ksplit,
                 long sA, long sB, long sC,
                 int lda, int ldb, int ldc)
{
    const int bz = blockIdx.z;
    const float* Ab0 = A0 + (long)bz * sA;
    const float* Ab1 = A1 + (long)bz * sA;
    const float* Bb  = B  + (long)bz * sB;
    float* Cb = C + (long)bz * sC;

    const int tid = threadIdx.x;          // 0..255
    const int tx = tid & 15;              // 16x16 thread grid
    const int ty = tid >> 4;
    const int row0 = blockIdx.y * BM;
    const int col0 = blockIdx.x * BN;

    __shared__ float As[BK][BM + 4];
    __shared__ float Bs[BK][BN + 4];

    float acc[4][4] = {};

    for (int k0 = 0; k0 < K; k0 += BK) {
        const float* Ap; int kk;
        if (k0 < Ksplit) { Ap = Ab0; kk = k0; }
        else             { Ap = Ab1; kk = k0 - Ksplit; }

        if (!TRANS_A) {
            const int k  = tid & 15;
            const int mb = tid >> 4;
            #pragma unroll
            for (int i = 0; i < 4; ++i) {
                const int m = mb + i * 16;
                As[k][m] = Ap[(long)(row0 + m) * lda + (kk + k)];
            }
        } else {
            const int m  = tid & 63;
            const int kb = tid >> 6;
            #pragma unroll
            for (int i = 0; i < 4; ++i) {
                const int k = kb + i * 4;
                As[k][m] = Ap[(long)(kk + k) * lda + (row0 + m)];
            }
        }
        if (!TRANS_B) {
            const int n  = tid & 63;
            const int kb = tid >> 6;
            #pragma unroll
            for (int i = 0; i < 4; ++i) {
                const int k = kb + i * 4;
                Bs[k][n] = Bb[(long)(k0 + k) * ldb + (col0 + n)];
            }
        } else {
            const int k  = tid & 15;
            const int nb = tid >> 4;
            #pragma unroll
            for (int i = 0; i < 4; ++i) {
                const int n = nb + i * 16;
                Bs[k][n] = Bb[(long)(col0 + n) * ldb + (k0 + k)];
            }
        }
        __syncthreads();
        #pragma unroll
        for (int k = 0; k < BK; ++k) {
            float a[4], b[4];
            #pragma unroll
            for (int i = 0; i < 4; ++i) a[i] = As[k][ty * 4 + i];
            #pragma unroll
            for (int j = 0; j < 4; ++j) b[j] = Bs[k][tx * 4 + j];
            #pragma unroll
            for (int i = 0; i < 4; ++i)
                #pragma unroll
                for (int j = 0; j < 4; ++j)
                    acc[i][j] = fmaf(a[i], b[j], acc[i][j]);
        }
        __syncthreads();
    }

    #pragma unroll
    for (int i = 0; i < 4; ++i) {
        const int r = row0 + ty * 4 + i;
        int mi = 0;
        float rmv = 1.0f;
        if (ROWMASK || PAIRMASK) mi = rm1[(long)bz * M + r];
        if (ROWMASK) rmv = (float)mi;
        #pragma unroll
        for (int j = 0; j < 4; ++j) {
            const int c = col0 + tx * 4 + j;
            float v = acc[i][j];
            if (BIAS) v += bias[c];
            if (DO_LRELU) v = lrelu_f(v);
            if (ROWMASK) v *= rmv;
            if (PAIRMASK) {
                const int mj = rm2[(long)bz * N + c];
                if (!(mi && mj)) v += NEG_BIG;
            }
            Cb[(long)r * ldc + c] = v;
        }
    }
}

// One wave per row (4 rows per block): max + sum(exp) -> store max and 1/sum
__global__ __launch_bounds__(256)
void row_stats(const float* __restrict__ o, float* __restrict__ rmax,
               float* __restrict__ rsinv, int L)
{
    const int row  = blockIdx.x * 4 + (threadIdx.x >> 6);
    const int lane = threadIdx.x & 63;
    const float* p = o + (long)row * L;
    float m = -3.0e38f;
    for (int j = lane; j < L; j += 64) m = fmaxf(m, p[j]);
    #pragma unroll
    for (int off = 32; off > 0; off >>= 1) m = fmaxf(m, __shfl_xor(m, off));
    float s = 0.0f;
    for (int j = lane; j < L; j += 64) s += __expf(p[j] - m);
    #pragma unroll
    for (int off = 32; off > 0; off >>= 1) s += __shfl_xor(s, off);
    if (lane == 0) { rmax[row] = m; rsinv[row] = 1.0f / s; }
}

// One thread per column, online softmax scan down the rows (coalesced across threads)
__global__ __launch_bounds__(256)
void col_stats(const float* __restrict__ o, float* __restrict__ cmax,
               float* __restrict__ csinv, int L)
{
    const int b = blockIdx.y;
    const int j = blockIdx.x * blockDim.x + threadIdx.x;
    const float* p = o + (long)b * L * L + j;
    float m = -3.0e38f;
    float s = 0.0f;
    for (int i = 0; i < L; ++i) {
        const float x = p[(long)i * L];
        const float mn = fmaxf(m, x);
        s = s * __expf(m - mn) + __expf(x - mn);
        m = mn;
    }
    cmax[b * L + j]  = m;
    csinv[b * L + j] = 1.0f / s;
}

// Elementwise: o1 = row-softmax * mpos, o2 = col-softmax * mpos (o2 may alias o)
__global__ __launch_bounds__(256)
void softmax_apply(const float* __restrict__ o, float* __restrict__ o1,
                   float* __restrict__ o2,
                   const float* __restrict__ rmax, const float* __restrict__ rsinv,
                   const float* __restrict__ cmax, const float* __restrict__ csinv,
                   const int* __restrict__ m1, const int* __restrict__ m2)
{
    const long idx = (long)blockIdx.x * blockDim.x + threadIdx.x;
    const int j = (int)(idx & 511);
    const int i = (int)((idx >> 9) & 511);
    const int b = (int)(idx >> 18);
    const int row = b * 512 + i;
    const int col = b * 512 + j;
    const float x  = o[idx];
    const float mp = (m1[row] != 0 && m2[col] != 0) ? 1.0f : 0.0f;
    o1[idx] = __expf(x - rmax[row]) * rsinv[row] * mp;
    o2[idx] = __expf(x - cmax[col]) * csinv[col] * mp;
}

extern "C" void kernel_launch(void* const* d_in, const int* in_sizes, int n_in,
                              void* d_out, int out_size, void* d_ws, size_t ws_size,
                              hipStream_t stream)
{
    const float* r1  = (const float*)d_in[0];
    const float* r2  = (const float*)d_in[1];
    const int*   m1  = (const int*)d_in[2];
    const int*   m2  = (const int*)d_in[3];
    const float* W1  = (const float*)d_in[4];
    const float* b1v = (const float*)d_in[5];
    const float* W2  = (const float*)d_in[6];
    const float* b2v = (const float*)d_in[7];
    const float* Wc1 = (const float*)d_in[8];
    const float* bc1 = (const float*)d_in[9];
    const float* Wc2 = (const float*)d_in[10];
    const float* bc2 = (const float*)d_in[11];
    float* out = (float*)d_out;

    constexpr int  Bn = 64, L = 512, D = 512;
    constexpr long CE = (long)Bn * L * D;    // 16,777,216 elems per [B,L,D] tensor
    constexpr int  NR = Bn * L;              // 32768 rows total

    // Workspace layout (3 big buffers + stats):
    float* ws    = (float*)d_ws;
    float* r1m   = ws;                 // [B,L,D]
    float* r2m   = ws + CE;            // [B,L,D]
    float* obuf  = ws + 2 * CE;        // o -> o2 (in place) -> hc1/hc2
    float* rmaxv = ws + 3 * CE;
    float* rsinv = rmaxv + NR;
    float* cmaxv = rsinv + NR;
    float* csinv = cmaxv + NR;

    // d_out doubles as scratch (fully rewritten by the final two GEMMs):
    float* hbuf  = out;        // h (mlp hidden) then r1_c
    float* o1buf = out + CE;   // o1 then r2_c

    dim3 blk(256);
    dim3 gNB(D / BN, NR / BM, 1);       // dense 32768 x 512 GEMMs
    dim3 gBat(L / BN, L / BM, Bn);      // batched 512x512x512 GEMMs
    const long S = (long)L * L;         // 262144 batch stride

    // 1) h = lrelu(r1 @ W1 + b1)
    gemm_kernel<false,false,true,true,false,false><<<gNB, blk, 0, stream>>>(
        r1, r1, W1, b1v, nullptr, nullptr, hbuf, NR, D, D, D, 0, 0, 0, D, D, D);
    // 2) r1m = lrelu(h @ W2 + b2) * m1
    gemm_kernel<false,false,true,true,true,false><<<gNB, blk, 0, stream>>>(
        hbuf, hbuf, W2, b2v, m1, nullptr, r1m, NR, D, D, D, 0, 0, 0, D, D, D);
    // 3) h = lrelu(r2 @ W1 + b1)
    gemm_kernel<false,false,true,true,false,false><<<gNB, blk, 0, stream>>>(
        r2, r2, W1, b1v, nullptr, nullptr, hbuf, NR, D, D, D, 0, 0, 0, D, D, D);
    // 4) r2m = lrelu(h @ W2 + b2) * m2
    gemm_kernel<false,false,true,true,true,false><<<gNB, blk, 0, stream>>>(
        hbuf, hbuf, W2, b2v, m2, nullptr, r2m, NR, D, D, D, 0, 0, 0, D, D, D);
    // 5) o = r1m @ r2m^T + additive pair mask   (batched, B = r2m transposed)
    gemm_kernel<false,true,false,false,false,true><<<gBat, blk, 0, stream>>>(
        r1m, r1m, r2m, nullptr, m1, m2, obuf, L, L, D, D, S, S, S, D, D, L);
    // 6) row softmax stats
    row_stats<<<NR / 4, blk, 0, stream>>>(obuf, rmaxv, rsinv, L);
    // 7) col softmax stats
    col_stats<<<dim3(L / 256, Bn), blk, 0, stream>>>(obuf, cmaxv, csinv, L);
    // 8) o1 = rowsm(o)*mpos -> o1buf ; o2 = colsm(o)*mpos -> obuf (in place)
    softmax_apply<<<(unsigned)((Bn * S) / 256), blk, 0, stream>>>(
        obuf, o1buf, obuf, rmaxv, rsinv, cmaxv, csinv, m1, m2);
    // 9) r1_c = o1 @ r2m   (batched NN) -> hbuf
    gemm_kernel<false,false,false,false,false,false><<<gBat, blk, 0, stream>>>(
        o1buf, o1buf, r2m, nullptr, nullptr, nullptr, hbuf, L, D, L, L, S, S, S, L, D, D);
    // 10) r2_c = o2^T @ r1m (batched TN) -> o1buf
    gemm_kernel<true,false,false,false,false,false><<<gBat, blk, 0, stream>>>(
        obuf, obuf, r1m, nullptr, nullptr, nullptr, o1buf, L, D, L, L, S, S, S, L, D, D);
    // 11) hc1 = lrelu(cat(r1m, r1_c) @ Wc1 + bc1) -> obuf
    gemm_kernel<false,false,true,true,false,false><<<gNB, blk, 0, stream>>>(
        r1m, hbuf, Wc1, bc1, nullptr, nullptr, obuf, NR, D, 2 * D, D, 0, 0, 0, D, D, D);
    // 12) out1 = lrelu(hc1 @ Wc2 + bc2) * m1 -> out[0:CE]
    gemm_kernel<false,false,true,true,true,false><<<gNB, blk, 0, stream>>>(
        obuf, obuf, Wc2, bc2, m1, nullptr, out, NR, D, D, D, 0, 0, 0, D, D, D);
    // 13) hc2 = lrelu(cat(r2m, r2_c) @ Wc1 + bc1) -> obuf
    gemm_kernel<false,false,true,true,false,false><<<gNB, blk, 0, stream>>>(
        r2m, o1buf, Wc1, bc1, nullptr, nullptr, obuf, NR, D, 2 * D, D, 0, 0, 0, D, D, D);
    // 14) out2 = lrelu(hc2 @ Wc2 + bc2) * m2 -> out[CE:2CE]
    gemm_kernel<false,false,true,true,true,false><<<gNB, blk, 0, stream>>>(
        obuf, obuf, Wc2, bc2, m2, nullptr, out + CE, NR, D, D, D, 0, 0, 0, D, D, D);
}

// Round 2
// 949.797 us; speedup vs baseline: 3.5222x; 3.5222x over previous
//
#include <hip/hip_runtime.h>

#define LRELU_SLOPE 0.01f
#define NEG_BIG -1e10f

typedef unsigned short ushort_t;
typedef __bf16 bf16x8 __attribute__((ext_vector_type(8)));
typedef float f32x4 __attribute__((ext_vector_type(4)));

static __device__ __forceinline__ float lrelu_f(float x) {
    return x >= 0.0f ? x : LRELU_SLOPE * x;
}

// fp32 -> bf16 round-to-nearest-even
static __device__ __forceinline__ ushort_t f2bf(float f) {
    unsigned int u = __float_as_uint(f);
    u += 0x7fffu + ((u >> 16) & 1u);
    return (ushort_t)(u >> 16);
}

static __device__ __forceinline__ void gld_lds16(const ushort_t* g, ushort_t* l) {
    __builtin_amdgcn_global_load_lds((const __attribute__((address_space(1))) void*)g,
                                     (__attribute__((address_space(3))) void*)l,
                                     16, 0, 0);
}

// ---------------------------------------------------------------------------
// NT bf16 MFMA GEMM (m97 structure): C[m,n] = epi( sum_k A[m,k] * B[n,k] )
// A: [M,K] row-major bf16 (optionally concat of A0,A1 split at Ksplit)
// B: [N,K] row-major bf16
// 128x128 tile, 256 threads = 4 waves in 2x2, BK=32, 16x16x32 MFMA.
// All dims must be multiples of 128 (M,N) and 32 (K) -- true for this problem.
// ---------------------------------------------------------------------------
template<bool BIAS, bool LRELU, bool RM, bool PM, bool BF16OUT>
__global__ __launch_bounds__(256)
void gemm_nt(const ushort_t* __restrict__ A0, const ushort_t* __restrict__ A1,
             int Ksplit, int lda0, int lda1,
             const ushort_t* __restrict__ B, int ldb,
             const float* __restrict__ bias,
             const int* __restrict__ rm1, const int* __restrict__ rm2,
             void* __restrict__ C, int ldc,
             int M, int N, int K,
             long sA, long sB, long sC)
{
    __shared__ ushort_t As[128 * 32];
    __shared__ ushort_t Bs[128 * 32];

    const int bz   = blockIdx.z;
    const int tid  = threadIdx.x;
    const int w    = tid >> 6;        // wave 0..3
    const int lane = tid & 63;
    const int wm   = w & 1;           // wave row (2x2)
    const int wn   = w >> 1;          // wave col
    const int row0 = blockIdx.y * 128;
    const int col0 = blockIdx.x * 128;

    const ushort_t* Ab0 = A0 + (long)bz * sA;
    const ushort_t* Ab1 = A1 + (long)bz * sA;
    const ushort_t* Bb  = B  + (long)bz * sB;

    // staging constants: wave w stages LDS ushort chunks [w*1024 + c*512)
    const int sRow = w * 32 + (lane >> 2);       // + c*16
    const int sOff = (lane & 3) * 8;             // k elems within 32-chunk
    ushort_t* ldsA0 = &As[w * 1024];
    ushort_t* ldsA1 = &As[w * 1024 + 512];
    ushort_t* ldsB0 = &Bs[w * 1024];
    ushort_t* ldsB1 = &Bs[w * 1024 + 512];

    const int lr = lane & 15, q = lane >> 4;
    // fragment LDS ushort offsets
    const int aBase = (wm * 64 + lr) * 32 + q * 8;
    const int bBase = (wn * 64 + lr) * 32 + q * 8;

    f32x4 acc[4][4] = {};

    for (int k0 = 0; k0 < K; k0 += 32) {
        const ushort_t* Ap; int kk, ldaP;
        if (k0 < Ksplit) { Ap = Ab0; kk = k0;          ldaP = lda0; }
        else             { Ap = Ab1; kk = k0 - Ksplit; ldaP = lda1; }

        gld_lds16(Ap + (size_t)(row0 + sRow) * ldaP + kk + sOff, ldsA0);
        gld_lds16(Ap + (size_t)(row0 + sRow + 16) * ldaP + kk + sOff, ldsA1);
        gld_lds16(Bb + (size_t)(col0 + sRow) * ldb + k0 + sOff, ldsB0);
        gld_lds16(Bb + (size_t)(col0 + sRow + 16) * ldb + k0 + sOff, ldsB1);

        __syncthreads();

        bf16x8 af[4], bf[4];
        #pragma unroll
        for (int i = 0; i < 4; ++i)
            af[i] = *reinterpret_cast<const bf16x8*>(&As[aBase + i * 16 * 32]);
        #pragma unroll
        for (int j = 0; j < 4; ++j)
            bf[j] = *reinterpret_cast<const bf16x8*>(&Bs[bBase + j * 16 * 32]);
        #pragma unroll
        for (int i = 0; i < 4; ++i)
            #pragma unroll
            for (int j = 0; j < 4; ++j)
                acc[i][j] = __builtin_amdgcn_mfma_f32_16x16x32_bf16(af[i], bf[j], acc[i][j], 0, 0, 0);

        __syncthreads();
    }

    // epilogue: C/D layout col=lane&15, row=(lane>>4)*4+reg
    float biasv[4];
    int mj[4];
    #pragma unroll
    for (int j = 0; j < 4; ++j) {
        const int c = col0 + wn * 64 + j * 16 + lr;
        if (BIAS) biasv[j] = bias[c];
        if (PM)   mj[j] = rm2[(long)bz * N + c];
    }
    float* Cf = (float*)C + (long)bz * sC;
    ushort_t* Ch = (ushort_t*)C + (long)bz * sC;

    #pragma unroll
    for (int i = 0; i < 4; ++i) {
        #pragma unroll
        for (int r = 0; r < 4; ++r) {
            const int row = row0 + wm * 64 + i * 16 + q * 4 + r;
            int mi = 0;
            if (RM || PM) mi = rm1[(long)bz * M + row];
            #pragma unroll
            for (int j = 0; j < 4; ++j) {
                const int c = col0 + wn * 64 + j * 16 + lr;
                float v = acc[i][j][r];
                if (BIAS) v += biasv[j];
                if (LRELU) v = lrelu_f(v);
                if (RM) v *= (float)mi;
                if (PM) { if (!(mi && mj[j])) v += NEG_BIG; }
                const size_t a = (size_t)row * ldc + c;
                if (BF16OUT) Ch[a] = f2bf(v); else Cf[a] = v;
            }
        }
    }
}

// ---------------------------------------------------------------------------
// fp32 -> bf16 elementwise convert (4 elems/thread)
__global__ __launch_bounds__(256)
void cvt_f32_bf16(const float* __restrict__ in, ushort_t* __restrict__ out, long n)
{
    const long i = ((long)blockIdx.x * 256 + threadIdx.x) * 4;
    const float4 v = *reinterpret_cast<const float4*>(in + i);
    ushort_t o[4] = { f2bf(v.x), f2bf(v.y), f2bf(v.z), f2bf(v.w) };
    *reinterpret_cast<uint2*>(out + i) = *reinterpret_cast<uint2*>(o);
}

// transpose fp32 [R,C] -> bf16 [C,R]
__global__ __launch_bounds__(256)
void transpose_cvt(const float* __restrict__ in, ushort_t* __restrict__ out, int R, int C)
{
    __shared__ float t[32][33];
    const int c0 = blockIdx.x * 32, r0 = blockIdx.y * 32;
    const int tx = threadIdx.x & 31, ty = threadIdx.x >> 5;
    #pragma unroll
    for (int p = 0; p < 4; ++p)
        t[ty + p * 8][tx] = in[(size_t)(r0 + ty + p * 8) * C + c0 + tx];
    __syncthreads();
    #pragma unroll
    for (int p = 0; p < 4; ++p)
        out[(size_t)(c0 + ty + p * 8) * R + r0 + tx] = f2bf(t[tx][ty + p * 8]);
}

// batched bf16 transpose: in [Bn][L][D] -> out [Bn][D][L]
__global__ __launch_bounds__(256)
void transpose_bf16(const ushort_t* __restrict__ in, ushort_t* __restrict__ out, int L, int D)
{
    __shared__ ushort_t t[32][33];
    const long bo = (long)blockIdx.z * L * D;
    const int d0 = blockIdx.x * 32, l0 = blockIdx.y * 32;
    const int tx = threadIdx.x & 31, ty = threadIdx.x >> 5;
    #pragma unroll
    for (int p = 0; p < 4; ++p)
        t[ty + p * 8][tx] = in[bo + (size_t)(l0 + ty + p * 8) * D + d0 + tx];
    __syncthreads();
    #pragma unroll
    for (int p = 0; p < 4; ++p)
        out[bo + (size_t)(d0 + ty + p * 8) * L + l0 + tx] = t[tx][ty + p * 8];
}

// one wave per row: max + 1/sum(exp)
__global__ __launch_bounds__(256)
void row_stats(const float* __restrict__ o, float* __restrict__ rmax,
               float* __restrict__ rsinv, int L)
{
    const int row  = blockIdx.x * 4 + (threadIdx.x >> 6);
    const int lane = threadIdx.x & 63;
    const float* p = o + (long)row * L;
    float m = -3.0e38f;
    for (int j = lane; j < L; j += 64) m = fmaxf(m, p[j]);
    #pragma unroll
    for (int off = 32; off > 0; off >>= 1) m = fmaxf(m, __shfl_xor(m, off));
    float s = 0.0f;
    for (int j = lane; j < L; j += 64) s += __expf(p[j] - m);
    #pragma unroll
    for (int off = 32; off > 0; off >>= 1) s += __shfl_xor(s, off);
    if (lane == 0) { rmax[row] = m; rsinv[row] = 1.0f / s; }
}

// one thread per column, online softmax scan
__global__ __launch_bounds__(256)
void col_stats(const float* __restrict__ o, float* __restrict__ cmax,
               float* __restrict__ csinv, int L)
{
    const int b = blockIdx.y;
    const int j = blockIdx.x * blockDim.x + threadIdx.x;
    const float* p = o + (long)b * L * L + j;
    float m = -3.0e38f;
    float s = 0.0f;
    for (int i = 0; i < L; ++i) {
        const float x = p[(long)i * L];
        const float mn = fmaxf(m, x);
        s = s * __expf(m - mn) + __expf(x - mn);
        m = mn;
    }
    cmax[b * L + j]  = m;
    csinv[b * L + j] = 1.0f / s;
}

// tiled: o1[b,i,j] = rowsm * mpos (bf16), o2T[b,j,i] = colsm * mpos (bf16)
__global__ __launch_bounds__(256)
void softmax_apply(const float* __restrict__ o,
                   ushort_t* __restrict__ o1, ushort_t* __restrict__ o2T,
                   const float* __restrict__ rmax, const float* __restrict__ rsinv,
                   const float* __restrict__ cmax, const float* __restrict__ csinv,
                   const int* __restrict__ m1, const int* __restrict__ m2)
{
    __shared__ ushort_t t[32][33];
    const int b = blockIdx.z;
    const long bo = (long)b * 512 * 512;
    const int j0 = blockIdx.x * 32, i0 = blockIdx.y * 32;
    const int tx = threadIdx.x & 31, ty = threadIdx.x >> 5;
    const int col = b * 512 + j0 + tx;
    const int mjv = m2[col];
    const float cm = cmax[col], cs = csinv[col];
    #pragma unroll
    for (int p = 0; p < 4; ++p) {
        const int i = i0 + ty + p * 8;
        const int row = b * 512 + i;
        const float x = o[bo + (long)i * 512 + j0 + tx];
        const float mp = (m1[row] != 0 && mjv != 0) ? 1.0f : 0.0f;
        o1[bo + (long)i * 512 + j0 + tx] = f2bf(__expf(x - rmax[row]) * rsinv[row] * mp);
        t[ty + p * 8][tx] = f2bf(__expf(x - cm) * cs * mp);
    }
    __syncthreads();
    #pragma unroll
    for (int p = 0; p < 4; ++p)
        o2T[bo + (long)(j0 + ty + p * 8) * 512 + i0 + tx] = t[tx][ty + p * 8];
}

// ---------------------------------------------------------------------------
extern "C" void kernel_launch(void* const* d_in, const int* in_sizes, int n_in,
                              void* d_out, int out_size, void* d_ws, size_t ws_size,
                              hipStream_t stream)
{
    const float* r1  = (const float*)d_in[0];
    const float* r2  = (const float*)d_in[1];
    const int*   m1  = (const int*)d_in[2];
    const int*   m2  = (const int*)d_in[3];
    const float* W1  = (const float*)d_in[4];
    const float* b1v = (const float*)d_in[5];
    const float* W2  = (const float*)d_in[6];
    const float* b2v = (const float*)d_in[7];
    const float* Wc1 = (const float*)d_in[8];
    const float* bc1 = (const float*)d_in[9];
    const float* Wc2 = (const float*)d_in[10];
    const float* bc2 = (const float*)d_in[11];
    float* out = (float*)d_out;

    constexpr int  Bn = 64, L = 512, D = 512;
    constexpr long CE = (long)Bn * L * D;  // 16,777,216
    constexpr long S  = (long)L * L;       // 262,144
    constexpr int  NR = Bn * L;            // 32,768

    // d_out as 4 bf16 scratch slots (all dead before final fp32 writes):
    ushort_t* O    = (ushort_t*)d_out;
    ushort_t* r1b  = O;            // slot0: r1 bf16, dead after gemm#1
    ushort_t* r2b  = O + CE;       // slot1: r2 bf16, dead after gemm#3
    ushort_t* r2mT = O;            // slot0 reuse
    ushort_t* r1mT = O + CE;       // slot1 reuse
    ushort_t* o1b  = O + 2 * CE;   // slot2
    ushort_t* o2Tb = O + 3 * CE;   // slot3

    // workspace
    char* wsb = (char*)d_ws;
    float*    obuf = (float*)wsb;                    // CE fp32 scores (dead after softmax)
    ushort_t* r1c  = (ushort_t*)wsb;                 // reuse obuf lo
    ushort_t* r2c  = (ushort_t*)wsb + CE;            // reuse obuf hi
    ushort_t* hb   = (ushort_t*)(wsb + 4 * CE);      // hidden bf16
    ushort_t* r1mb = (ushort_t*)(wsb + 6 * CE);
    ushort_t* r2mb = (ushort_t*)(wsb + 8 * CE);
    ushort_t* W1t  = (ushort_t*)(wsb + 10 * CE);
    ushort_t* W2t  = W1t + 512 * 512;
    ushort_t* Wc1t = W2t + 512 * 512;                // [512,1024]
    ushort_t* Wc2t = Wc1t + 512 * 1024;
    float* rmaxv = (float*)(wsb + 10 * CE + 8 * 1024 * 1024);
    float* rsinv = rmaxv + NR;
    float* cmaxv = rsinv + NR;
    float* csinv = cmaxv + NR;

    const dim3 blk(256);
    const dim3 gD(D / 128, NR / 128, 1);   // dense: 4 x 256
    const dim3 gB(L / 128, L / 128, Bn);   // batched: 4 x 4 x 64

    // 0) convert inputs + weights
    cvt_f32_bf16<<<dim3(CE / 1024), blk, 0, stream>>>(r1, r1b, CE);
    cvt_f32_bf16<<<dim3(CE / 1024), blk, 0, stream>>>(r2, r2b, CE);
    transpose_cvt<<<dim3(16, 16), blk, 0, stream>>>(W1, W1t, 512, 512);
    transpose_cvt<<<dim3(16, 16), blk, 0, stream>>>(W2, W2t, 512, 512);
    transpose_cvt<<<dim3(16, 32), blk, 0, stream>>>(Wc1, Wc1t, 1024, 512);
    transpose_cvt<<<dim3(16, 16), blk, 0, stream>>>(Wc2, Wc2t, 512, 512);

    // 1) h = lrelu(r1 @ W1 + b1)
    gemm_nt<true,true,false,false,true><<<gD, blk, 0, stream>>>(
        r1b, r1b, D, D, D, W1t, D, b1v, nullptr, nullptr, hb, D, NR, D, D, 0, 0, 0);
    // 2) r1m = lrelu(h @ W2 + b2) * m1
    gemm_nt<true,true,true,false,true><<<gD, blk, 0, stream>>>(
        hb, hb, D, D, D, W2t, D, b2v, m1, nullptr, r1mb, D, NR, D, D, 0, 0, 0);
    // 3) h = lrelu(r2 @ W1 + b1)
    gemm_nt<true,true,false,false,true><<<gD, blk, 0, stream>>>(
        r2b, r2b, D, D, D, W1t, D, b1v, nullptr, nullptr, hb, D, NR, D, D, 0, 0, 0);
    // 4) r2m = lrelu(h @ W2 + b2) * m2
    gemm_nt<true,true,true,false,true><<<gD, blk, 0, stream>>>(
        hb, hb, D, D, D, W2t, D, b2v, m2, nullptr, r2mb, D, NR, D, D, 0, 0, 0);
    // 5) o = r1m @ r2m^T + pairmask  (fp32 out)
    gemm_nt<false,false,false,true,false><<<gB, blk, 0, stream>>>(
        r1mb, r1mb, D, D, D, r2mb, D, nullptr, m1, m2, obuf, L, L, L, D, S, S, S);
    // 6) softmax stats
    row_stats<<<dim3(NR / 4), blk, 0, stream>>>(obuf, rmaxv, rsinv, L);
    col_stats<<<dim3(L / 256, Bn), blk, 0, stream>>>(obuf, cmaxv, csinv, L);
    // 7) transposed copies for ctx GEMMs (into dead d_out slots)
    transpose_bf16<<<dim3(16, 16, Bn), blk, 0, stream>>>(r2mb, r2mT, L, D);
    transpose_bf16<<<dim3(16, 16, Bn), blk, 0, stream>>>(r1mb, r1mT, L, D);
    // 8) o1 (bf16) + o2^T (bf16)
    softmax_apply<<<dim3(16, 16, Bn), blk, 0, stream>>>(
        obuf, o1b, o2Tb, rmaxv, rsinv, cmaxv, csinv, m1, m2);
    // 9) r1_c = o1 @ r2m  (NT with r2mT)
    gemm_nt<false,false,false,false,true><<<gB, blk, 0, stream>>>(
        o1b, o1b, L, L, L, r2mT, L, nullptr, nullptr, nullptr, r1c, D, L, D, L, S, S, S);
    // 10) r2_c = o2^T @ r1m (NT with o2T, r1mT)
    gemm_nt<false,false,false,false,true><<<gB, blk, 0, stream>>>(
        o2Tb, o2Tb, L, L, L, r1mT, L, nullptr, nullptr, nullptr, r2c, D, L, D, L, S, S, S);
    // 11) hc1 = lrelu(cat(r1m, r1_c) @ Wc1 + bc1)
    gemm_nt<true,true,false,false,true><<<gD, blk, 0, stream>>>(
        r1mb, r1c, D, D, D, Wc1t, 2 * D, bc1, nullptr, nullptr, hb, D, NR, D, 2 * D, 0, 0, 0);
    // 12) out1 = lrelu(hc1 @ Wc2 + bc2) * m1  (fp32)
    gemm_nt<true,true,true,false,false><<<gD, blk, 0, stream>>>(
        hb, hb, D, D, D, Wc2t, D, bc2, m1, nullptr, out, D, NR, D, D, 0, 0, 0);
    // 13) hc2 = lrelu(cat(r2m, r2_c) @ Wc1 + bc1)
    gemm_nt<true,true,false,false,true><<<gD, blk, 0, stream>>>(
        r2mb, r2c, D, D, D, Wc1t, 2 * D, bc1, nullptr, nullptr, hb, D, NR, D, 2 * D, 0, 0, 0);
    // 14) out2 = lrelu(hc2 @ Wc2 + bc2) * m2  (fp32)
    gemm_nt<true,true,true,false,false><<<gD, blk, 0, stream>>>(
        hb, hb, D, D, D, Wc2t, D, bc2, m2, nullptr, out + CE, D, NR, D, D, 0, 0, 0);
}

// Round 3
// 824.780 us; speedup vs baseline: 4.0561x; 1.1516x over previous
//
#include <hip/hip_runtime.h>

#define LRELU_SLOPE 0.01f
#define NEG_BIG -1e10f

typedef unsigned short ushort_t;
typedef __bf16 bf16x8 __attribute__((ext_vector_type(8)));
typedef float f32x4 __attribute__((ext_vector_type(4)));

static __device__ __forceinline__ float lrelu_f(float x) {
    return x >= 0.0f ? x : LRELU_SLOPE * x;
}

// fp32 -> bf16 round-to-nearest-even
static __device__ __forceinline__ ushort_t f2bf(float f) {
    unsigned int u = __float_as_uint(f);
    u += 0x7fffu + ((u >> 16) & 1u);
    return (ushort_t)(u >> 16);
}

static __device__ __forceinline__ void gld_lds16(const ushort_t* g, ushort_t* l) {
    __builtin_amdgcn_global_load_lds((const __attribute__((address_space(1))) void*)g,
                                     (__attribute__((address_space(3))) void*)l,
                                     16, 0, 0);
}

// ---------------------------------------------------------------------------
// NT bf16 MFMA GEMM (m97 structure): C[m,n] = epi( sum_k A[m,k] * B[n,k] )
// 128x128 tile, 256 threads = 4 waves in 2x2, BK=32, 16x16x32 MFMA.
// ---------------------------------------------------------------------------
template<bool BIAS, bool LRELU, bool RM, bool PM, bool BF16OUT>
__global__ __launch_bounds__(256)
void gemm_nt(const ushort_t* __restrict__ A0, const ushort_t* __restrict__ A1,
             int Ksplit, int lda0, int lda1,
             const ushort_t* __restrict__ B, int ldb,
             const float* __restrict__ bias,
             const int* __restrict__ rm1, const int* __restrict__ rm2,
             void* __restrict__ C, int ldc,
             int M, int N, int K,
             long sA, long sB, long sC)
{
    __shared__ ushort_t As[128 * 32];
    __shared__ ushort_t Bs[128 * 32];

    const int bz   = blockIdx.z;
    const int tid  = threadIdx.x;
    const int w    = tid >> 6;        // wave 0..3
    const int lane = tid & 63;
    const int wm   = w & 1;           // wave row (2x2)
    const int wn   = w >> 1;          // wave col
    const int row0 = blockIdx.y * 128;
    const int col0 = blockIdx.x * 128;

    const ushort_t* Ab0 = A0 + (long)bz * sA;
    const ushort_t* Ab1 = A1 + (long)bz * sA;
    const ushort_t* Bb  = B  + (long)bz * sB;

    const int sRow = w * 32 + (lane >> 2);
    const int sOff = (lane & 3) * 8;
    ushort_t* ldsA0 = &As[w * 1024];
    ushort_t* ldsA1 = &As[w * 1024 + 512];
    ushort_t* ldsB0 = &Bs[w * 1024];
    ushort_t* ldsB1 = &Bs[w * 1024 + 512];

    const int lr = lane & 15, q = lane >> 4;
    const int aBase = (wm * 64 + lr) * 32 + q * 8;
    const int bBase = (wn * 64 + lr) * 32 + q * 8;

    f32x4 acc[4][4] = {};

    for (int k0 = 0; k0 < K; k0 += 32) {
        const ushort_t* Ap; int kk, ldaP;
        if (k0 < Ksplit) { Ap = Ab0; kk = k0;          ldaP = lda0; }
        else             { Ap = Ab1; kk = k0 - Ksplit; ldaP = lda1; }

        gld_lds16(Ap + (size_t)(row0 + sRow) * ldaP + kk + sOff, ldsA0);
        gld_lds16(Ap + (size_t)(row0 + sRow + 16) * ldaP + kk + sOff, ldsA1);
        gld_lds16(Bb + (size_t)(col0 + sRow) * ldb + k0 + sOff, ldsB0);
        gld_lds16(Bb + (size_t)(col0 + sRow + 16) * ldb + k0 + sOff, ldsB1);

        __syncthreads();

        bf16x8 af[4], bf[4];
        #pragma unroll
        for (int i = 0; i < 4; ++i)
            af[i] = *reinterpret_cast<const bf16x8*>(&As[aBase + i * 16 * 32]);
        #pragma unroll
        for (int j = 0; j < 4; ++j)
            bf[j] = *reinterpret_cast<const bf16x8*>(&Bs[bBase + j * 16 * 32]);
        #pragma unroll
        for (int i = 0; i < 4; ++i)
            #pragma unroll
            for (int j = 0; j < 4; ++j)
                acc[i][j] = __builtin_amdgcn_mfma_f32_16x16x32_bf16(af[i], bf[j], acc[i][j], 0, 0, 0);

        __syncthreads();
    }

    float biasv[4];
    int mj[4];
    #pragma unroll
    for (int j = 0; j < 4; ++j) {
        const int c = col0 + wn * 64 + j * 16 + lr;
        if (BIAS) biasv[j] = bias[c];
        if (PM)   mj[j] = rm2[(long)bz * N + c];
    }
    float* Cf = (float*)C + (long)bz * sC;
    ushort_t* Ch = (ushort_t*)C + (long)bz * sC;

    #pragma unroll
    for (int i = 0; i < 4; ++i) {
        #pragma unroll
        for (int r = 0; r < 4; ++r) {
            const int row = row0 + wm * 64 + i * 16 + q * 4 + r;
            int mi = 0;
            if (RM || PM) mi = rm1[(long)bz * M + row];
            #pragma unroll
            for (int j = 0; j < 4; ++j) {
                const int c = col0 + wn * 64 + j * 16 + lr;
                float v = acc[i][j][r];
                if (BIAS) v += biasv[j];
                if (LRELU) v = lrelu_f(v);
                if (RM) v *= (float)mi;
                if (PM) { if (!(mi && mj[j])) v += NEG_BIG; }
                const size_t a = (size_t)row * ldc + c;
                if (BF16OUT) Ch[a] = f2bf(v); else Cf[a] = v;
            }
        }
    }
}

// ---------------------------------------------------------------------------
__global__ __launch_bounds__(256)
void cvt_f32_bf16(const float* __restrict__ in, ushort_t* __restrict__ out, long n)
{
    const long i = ((long)blockIdx.x * 256 + threadIdx.x) * 4;
    const float4 v = *reinterpret_cast<const float4*>(in + i);
    ushort_t o[4] = { f2bf(v.x), f2bf(v.y), f2bf(v.z), f2bf(v.w) };
    *reinterpret_cast<uint2*>(out + i) = *reinterpret_cast<uint2*>(o);
}

// transpose fp32 [R,C] -> bf16 [C,R]
__global__ __launch_bounds__(256)
void transpose_cvt(const float* __restrict__ in, ushort_t* __restrict__ out, int R, int C)
{
    __shared__ float t[32][33];
    const int c0 = blockIdx.x * 32, r0 = blockIdx.y * 32;
    const int tx = threadIdx.x & 31, ty = threadIdx.x >> 5;
    #pragma unroll
    for (int p = 0; p < 4; ++p)
        t[ty + p * 8][tx] = in[(size_t)(r0 + ty + p * 8) * C + c0 + tx];
    __syncthreads();
    #pragma unroll
    for (int p = 0; p < 4; ++p)
        out[(size_t)(c0 + ty + p * 8) * R + r0 + tx] = f2bf(t[tx][ty + p * 8]);
}

// batched bf16 transpose: in [Bn][L][D] -> out [Bn][D][L]
__global__ __launch_bounds__(256)
void transpose_bf16(const ushort_t* __restrict__ in, ushort_t* __restrict__ out, int L, int D)
{
    __shared__ ushort_t t[32][33];
    const long bo = (long)blockIdx.z * L * D;
    const int d0 = blockIdx.x * 32, l0 = blockIdx.y * 32;
    const int tx = threadIdx.x & 31, ty = threadIdx.x >> 5;
    #pragma unroll
    for (int p = 0; p < 4; ++p)
        t[ty + p * 8][tx] = in[bo + (size_t)(l0 + ty + p * 8) * D + d0 + tx];
    __syncthreads();
    #pragma unroll
    for (int p = 0; p < 4; ++p)
        out[bo + (size_t)(d0 + ty + p * 8) * L + l0 + tx] = t[tx][ty + p * 8];
}

// one wave per row: max + 1/sum(exp)
__global__ __launch_bounds__(256)
void row_stats(const float* __restrict__ o, float* __restrict__ rmax,
               float* __restrict__ rsinv, int L)
{
    const int row  = blockIdx.x * 4 + (threadIdx.x >> 6);
    const int lane = threadIdx.x & 63;
    const float* p = o + (long)row * L;
    float m = -3.0e38f;
    for (int j = lane; j < L; j += 64) m = fmaxf(m, p[j]);
    #pragma unroll
    for (int off = 32; off > 0; off >>= 1) m = fmaxf(m, __shfl_xor(m, off));
    float s = 0.0f;
    for (int j = lane; j < L; j += 64) s += __expf(p[j] - m);
    #pragma unroll
    for (int off = 32; off > 0; off >>= 1) s += __shfl_xor(s, off);
    if (lane == 0) { rmax[row] = m; rsinv[row] = 1.0f / s; }
}

// column stats phase 1: each block scans 64 rows for 256 columns (split-K)
__global__ __launch_bounds__(256)
void col_part(const float* __restrict__ o, float* __restrict__ pm,
              float* __restrict__ ps, int L)
{
    const int b  = blockIdx.z;
    const int rc = blockIdx.y;                       // row chunk 0..7
    const int j  = blockIdx.x * 256 + threadIdx.x;   // column
    const float* p = o + (long)b * L * L + (long)rc * 64 * L + j;
    float m = -3.0e38f, s = 0.0f;
    #pragma unroll 4
    for (int i = 0; i < 64; ++i) {
        const float x = p[(long)i * L];
        const float mn = fmaxf(m, x);
        s = s * __expf(m - mn) + __expf(x - mn);
        m = mn;
    }
    const long idx = ((long)b * 8 + rc) * L + j;
    pm[idx] = m;
    ps[idx] = s;
}

// column stats phase 2: merge 8 partials per column
__global__ __launch_bounds__(256)
void col_combine(const float* __restrict__ pm, const float* __restrict__ ps,
                 float* __restrict__ cmax, float* __restrict__ csinv, int L)
{
    const int b = blockIdx.y;
    const int j = blockIdx.x * 256 + threadIdx.x;
    float mk[8], sk[8];
    #pragma unroll
    for (int k = 0; k < 8; ++k) {
        mk[k] = pm[((long)b * 8 + k) * L + j];
        sk[k] = ps[((long)b * 8 + k) * L + j];
    }
    float m = -3.0e38f;
    #pragma unroll
    for (int k = 0; k < 8; ++k) m = fmaxf(m, mk[k]);
    float s = 0.0f;
    #pragma unroll
    for (int k = 0; k < 8; ++k) s += sk[k] * __expf(mk[k] - m);
    cmax[b * L + j]  = m;
    csinv[b * L + j] = 1.0f / s;
}

// tiled: o1[b,i,j] = rowsm * mpos (bf16), o2T[b,j,i] = colsm * mpos (bf16)
__global__ __launch_bounds__(256)
void softmax_apply(const float* __restrict__ o,
                   ushort_t* __restrict__ o1, ushort_t* __restrict__ o2T,
                   const float* __restrict__ rmax, const float* __restrict__ rsinv,
                   const float* __restrict__ cmax, const float* __restrict__ csinv,
                   const int* __restrict__ m1, const int* __restrict__ m2)
{
    __shared__ ushort_t t[32][33];
    const int b = blockIdx.z;
    const long bo = (long)b * 512 * 512;
    const int j0 = blockIdx.x * 32, i0 = blockIdx.y * 32;
    const int tx = threadIdx.x & 31, ty = threadIdx.x >> 5;
    const int col = b * 512 + j0 + tx;
    const int mjv = m2[col];
    const float cm = cmax[col], cs = csinv[col];
    #pragma unroll
    for (int p = 0; p < 4; ++p) {
        const int i = i0 + ty + p * 8;
        const int row = b * 512 + i;
        const float x = o[bo + (long)i * 512 + j0 + tx];
        const float mp = (m1[row] != 0 && mjv != 0) ? 1.0f : 0.0f;
        o1[bo + (long)i * 512 + j0 + tx] = f2bf(__expf(x - rmax[row]) * rsinv[row] * mp);
        t[ty + p * 8][tx] = f2bf(__expf(x - cm) * cs * mp);
    }
    __syncthreads();
    #pragma unroll
    for (int p = 0; p < 4; ++p)
        o2T[bo + (long)(j0 + ty + p * 8) * 512 + i0 + tx] = t[tx][ty + p * 8];
}

// ---------------------------------------------------------------------------
extern "C" void kernel_launch(void* const* d_in, const int* in_sizes, int n_in,
                              void* d_out, int out_size, void* d_ws, size_t ws_size,
                              hipStream_t stream)
{
    const float* r1  = (const float*)d_in[0];
    const float* r2  = (const float*)d_in[1];
    const int*   m1  = (const int*)d_in[2];
    const int*   m2  = (const int*)d_in[3];
    const float* W1  = (const float*)d_in[4];
    const float* b1v = (const float*)d_in[5];
    const float* W2  = (const float*)d_in[6];
    const float* b2v = (const float*)d_in[7];
    const float* Wc1 = (const float*)d_in[8];
    const float* bc1 = (const float*)d_in[9];
    const float* Wc2 = (const float*)d_in[10];
    const float* bc2 = (const float*)d_in[11];
    float* out = (float*)d_out;

    constexpr int  Bn = 64, L = 512, D = 512;
    constexpr long CE = (long)Bn * L * D;  // 16,777,216
    constexpr long S  = (long)L * L;       // 262,144
    constexpr int  NR = Bn * L;            // 32,768

    // d_out as 4 bf16 scratch slots (all dead before final fp32 writes):
    ushort_t* O    = (ushort_t*)d_out;
    ushort_t* r1b  = O;            // slot0: r1 bf16, dead after gemm#1
    ushort_t* r2b  = O + CE;       // slot1: r2 bf16, dead after gemm#3
    ushort_t* r2mT = O;            // slot0 reuse
    ushort_t* r1mT = O + CE;       // slot1 reuse
    ushort_t* o1b  = O + 2 * CE;   // slot2
    ushort_t* o2Tb = O + 3 * CE;   // slot3

    // workspace
    char* wsb = (char*)d_ws;
    float*    obuf = (float*)wsb;                    // CE fp32 scores (dead after softmax)
    ushort_t* r1c  = (ushort_t*)wsb;                 // reuse obuf lo
    ushort_t* r2c  = (ushort_t*)wsb + CE;            // reuse obuf hi
    ushort_t* hb   = (ushort_t*)(wsb + 4 * CE);      // hidden bf16
    ushort_t* r1mb = (ushort_t*)(wsb + 6 * CE);
    ushort_t* r2mb = (ushort_t*)(wsb + 8 * CE);
    ushort_t* W1t  = (ushort_t*)(wsb + 10 * CE);
    ushort_t* W2t  = W1t + 512 * 512;
    ushort_t* Wc1t = W2t + 512 * 512;                // [512,1024]
    ushort_t* Wc2t = Wc1t + 512 * 1024;
    float* rmaxv = (float*)(wsb + 10 * CE + 8 * 1024 * 1024);
    float* rsinv = rmaxv + NR;
    float* cmaxv = rsinv + NR;
    float* csinv = cmaxv + NR;
    float* pmbuf = csinv + NR;             // 8*512*64 = 262144 floats
    float* psbuf = pmbuf + 8 * L * Bn;

    const dim3 blk(256);
    const dim3 gD(D / 128, NR / 128, 1);   // dense: 4 x 256
    const dim3 gB(L / 128, L / 128, Bn);   // batched: 4 x 4 x 64

    // 0) convert inputs + weights
    cvt_f32_bf16<<<dim3(CE / 1024), blk, 0, stream>>>(r1, r1b, CE);
    cvt_f32_bf16<<<dim3(CE / 1024), blk, 0, stream>>>(r2, r2b, CE);
    transpose_cvt<<<dim3(16, 16), blk, 0, stream>>>(W1, W1t, 512, 512);
    transpose_cvt<<<dim3(16, 16), blk, 0, stream>>>(W2, W2t, 512, 512);
    transpose_cvt<<<dim3(16, 32), blk, 0, stream>>>(Wc1, Wc1t, 1024, 512);
    transpose_cvt<<<dim3(16, 16), blk, 0, stream>>>(Wc2, Wc2t, 512, 512);

    // 1) h = lrelu(r1 @ W1 + b1)
    gemm_nt<true,true,false,false,true><<<gD, blk, 0, stream>>>(
        r1b, r1b, D, D, D, W1t, D, b1v, nullptr, nullptr, hb, D, NR, D, D, 0, 0, 0);
    // 2) r1m = lrelu(h @ W2 + b2) * m1
    gemm_nt<true,true,true,false,true><<<gD, blk, 0, stream>>>(
        hb, hb, D, D, D, W2t, D, b2v, m1, nullptr, r1mb, D, NR, D, D, 0, 0, 0);
    // 3) h = lrelu(r2 @ W1 + b1)
    gemm_nt<true,true,false,false,true><<<gD, blk, 0, stream>>>(
        r2b, r2b, D, D, D, W1t, D, b1v, nullptr, nullptr, hb, D, NR, D, D, 0, 0, 0);
    // 4) r2m = lrelu(h @ W2 + b2) * m2
    gemm_nt<true,true,true,false,true><<<gD, blk, 0, stream>>>(
        hb, hb, D, D, D, W2t, D, b2v, m2, nullptr, r2mb, D, NR, D, D, 0, 0, 0);
    // 5) o = r1m @ r2m^T + pairmask  (fp32 out)
    gemm_nt<false,false,false,true,false><<<gB, blk, 0, stream>>>(
        r1mb, r1mb, D, D, D, r2mb, D, nullptr, m1, m2, obuf, L, L, L, D, S, S, S);
    // 6) softmax stats (row: 1 wave/row; col: split over 8 row-chunks + combine)
    row_stats<<<dim3(NR / 4), blk, 0, stream>>>(obuf, rmaxv, rsinv, L);
    col_part<<<dim3(L / 256, 8, Bn), blk, 0, stream>>>(obuf, pmbuf, psbuf, L);
    col_combine<<<dim3(L / 256, Bn), blk, 0, stream>>>(pmbuf, psbuf, cmaxv, csinv, L);
    // 7) transposed copies for ctx GEMMs (into dead d_out slots)
    transpose_bf16<<<dim3(16, 16, Bn), blk, 0, stream>>>(r2mb, r2mT, L, D);
    transpose_bf16<<<dim3(16, 16, Bn), blk, 0, stream>>>(r1mb, r1mT, L, D);
    // 8) o1 (bf16) + o2^T (bf16)
    softmax_apply<<<dim3(16, 16, Bn), blk, 0, stream>>>(
        obuf, o1b, o2Tb, rmaxv, rsinv, cmaxv, csinv, m1, m2);
    // 9) r1_c = o1 @ r2m  (NT with r2mT)
    gemm_nt<false,false,false,false,true><<<gB, blk, 0, stream>>>(
        o1b, o1b, L, L, L, r2mT, L, nullptr, nullptr, nullptr, r1c, D, L, D, L, S, S, S);
    // 10) r2_c = o2^T @ r1m (NT with o2T, r1mT)
    gemm_nt<false,false,false,false,true><<<gB, blk, 0, stream>>>(
        o2Tb, o2Tb, L, L, L, r1mT, L, nullptr, nullptr, nullptr, r2c, D, L, D, L, S, S, S);
    // 11) hc1 = lrelu(cat(r1m, r1_c) @ Wc1 + bc1)
    gemm_nt<true,true,false,false,true><<<gD, blk, 0, stream>>>(
        r1mb, r1c, D, D, D, Wc1t, 2 * D, bc1, nullptr, nullptr, hb, D, NR, D, 2 * D, 0, 0, 0);
    // 12) out1 = lrelu(hc1 @ Wc2 + bc2) * m1  (fp32)
    gemm_nt<true,true,true,false,false><<<gD, blk, 0, stream>>>(
        hb, hb, D, D, D, Wc2t, D, bc2, m1, nullptr, out, D, NR, D, D, 0, 0, 0);
    // 13) hc2 = lrelu(cat(r2m, r2_c) @ Wc1 + bc1)
    gemm_nt<true,true,false,false,true><<<gD, blk, 0, stream>>>(
        r2mb, r2c, D, D, D, Wc1t, 2 * D, bc1, nullptr, nullptr, hb, D, NR, D, 2 * D, 0, 0, 0);
    // 14) out2 = lrelu(hc2 @ Wc2 + bc2) * m2  (fp32)
    gemm_nt<true,true,true,false,false><<<gD, blk, 0, stream>>>(
        hb, hb, D, D, D, Wc2t, D, bc2, m2, nullptr, out + CE, D, NR, D, D, 0, 0, 0);
}

// Round 4
// 753.675 us; speedup vs baseline: 4.4387x; 1.0943x over previous
//
#include <hip/hip_runtime.h>

#define LRELU_SLOPE 0.01f
#define NEG_BIG -1e10f

typedef unsigned short ushort_t;
typedef __bf16 bf16x8 __attribute__((ext_vector_type(8)));
typedef float f32x4 __attribute__((ext_vector_type(4)));

static __device__ __forceinline__ float lrelu_f(float x) {
    return x >= 0.0f ? x : LRELU_SLOPE * x;
}

static __device__ __forceinline__ ushort_t f2bf(float f) {
    unsigned int u = __float_as_uint(f);
    u += 0x7fffu + ((u >> 16) & 1u);
    return (ushort_t)(u >> 16);
}

static __device__ __forceinline__ void gld_lds16(const ushort_t* g, ushort_t* l) {
    __builtin_amdgcn_global_load_lds((const __attribute__((address_space(1))) void*)g,
                                     (__attribute__((address_space(3))) void*)l,
                                     16, 0, 0);
}

// ---------------------------------------------------------------------------
// NT bf16 MFMA GEMM: C[m,n] = epi( sum_k A[m,k] * B[n,k] )
// 128x128 tile, 4 waves (2x2), BK=32, 16x16x32 MFMA.
// RM mask: row < Mhalf ? rm1[row] : rm2[row-Mhalf]  (combined-M launches)
// PM mask: rm1[bz*M+row] && rm2[bz*N+col] else += NEG_BIG (batched score GEMM)
// TWOUT: additionally store bf16 transposed per-batch:  CT[(row>>9)*S + col*512 + (row&511)]
// ---------------------------------------------------------------------------
template<bool BIAS, bool LRELU, bool RM, bool PM, bool BF16OUT, bool TWOUT>
__global__ __launch_bounds__(256)
void gemm_nt(const ushort_t* __restrict__ A0, const ushort_t* __restrict__ A1,
             int Ksplit, int lda0, int lda1,
             const ushort_t* __restrict__ B, int ldb,
             const float* __restrict__ bias,
             const int* __restrict__ rm1, const int* __restrict__ rm2,
             void* __restrict__ C, int ldc,
             ushort_t* __restrict__ CT, int Mhalf,
             int M, int N, int K,
             long sA, long sB, long sC)
{
    __shared__ ushort_t As[128 * 32];
    __shared__ ushort_t Bs[128 * 32];

    const int bz   = blockIdx.z;
    const int tid  = threadIdx.x;
    const int w    = tid >> 6;
    const int lane = tid & 63;
    const int wm   = w & 1;
    const int wn   = w >> 1;
    const int row0 = blockIdx.y * 128;
    const int col0 = blockIdx.x * 128;

    const ushort_t* Ab0 = A0 + (long)bz * sA;
    const ushort_t* Ab1 = A1 + (long)bz * sA;
    const ushort_t* Bb  = B  + (long)bz * sB;

    const int sRow = w * 32 + (lane >> 2);
    const int sOff = (lane & 3) * 8;
    ushort_t* ldsA0 = &As[w * 1024];
    ushort_t* ldsA1 = &As[w * 1024 + 512];
    ushort_t* ldsB0 = &Bs[w * 1024];
    ushort_t* ldsB1 = &Bs[w * 1024 + 512];

    const int lr = lane & 15, q = lane >> 4;
    const int aBase = (wm * 64 + lr) * 32 + q * 8;
    const int bBase = (wn * 64 + lr) * 32 + q * 8;

    f32x4 acc[4][4] = {};

    for (int k0 = 0; k0 < K; k0 += 32) {
        const ushort_t* Ap; int kk, ldaP;
        if (k0 < Ksplit) { Ap = Ab0; kk = k0;          ldaP = lda0; }
        else             { Ap = Ab1; kk = k0 - Ksplit; ldaP = lda1; }

        gld_lds16(Ap + (size_t)(row0 + sRow) * ldaP + kk + sOff, ldsA0);
        gld_lds16(Ap + (size_t)(row0 + sRow + 16) * ldaP + kk + sOff, ldsA1);
        gld_lds16(Bb + (size_t)(col0 + sRow) * ldb + k0 + sOff, ldsB0);
        gld_lds16(Bb + (size_t)(col0 + sRow + 16) * ldb + k0 + sOff, ldsB1);

        __syncthreads();

        bf16x8 af[4], bf[4];
        #pragma unroll
        for (int i = 0; i < 4; ++i)
            af[i] = *reinterpret_cast<const bf16x8*>(&As[aBase + i * 16 * 32]);
        #pragma unroll
        for (int j = 0; j < 4; ++j)
            bf[j] = *reinterpret_cast<const bf16x8*>(&Bs[bBase + j * 16 * 32]);
        #pragma unroll
        for (int i = 0; i < 4; ++i)
            #pragma unroll
            for (int j = 0; j < 4; ++j)
                acc[i][j] = __builtin_amdgcn_mfma_f32_16x16x32_bf16(af[i], bf[j], acc[i][j], 0, 0, 0);

        __syncthreads();
    }

    float biasv[4];
    int mj[4];
    #pragma unroll
    for (int j = 0; j < 4; ++j) {
        const int c = col0 + wn * 64 + j * 16 + lr;
        if (BIAS) biasv[j] = bias[c];
        if (PM)   mj[j] = rm2[(long)bz * N + c];
    }
    float* Cf = (float*)C + (long)bz * sC;
    ushort_t* Ch = (ushort_t*)C + (long)bz * sC;

    #pragma unroll
    for (int i = 0; i < 4; ++i) {
        const int rg0 = row0 + wm * 64 + i * 16 + q * 4;   // first of 4 consecutive rows
        int mi4[4];
        if (RM || PM) {
            #pragma unroll
            for (int r = 0; r < 4; ++r) {
                const int row = rg0 + r;
                if (PM)      mi4[r] = rm1[(long)bz * M + row];
                else         mi4[r] = (row < Mhalf) ? rm1[row] : rm2[row - Mhalf];
            }
        }
        #pragma unroll
        for (int j = 0; j < 4; ++j) {
            const int c = col0 + wn * 64 + j * 16 + lr;
            ushort_t tp[4];
            #pragma unroll
            for (int r = 0; r < 4; ++r) {
                const int row = rg0 + r;
                float v = acc[i][j][r];
                if (BIAS) v += biasv[j];
                if (LRELU) v = lrelu_f(v);
                if (RM) v *= (float)mi4[r];
                if (PM) { if (!(mi4[r] && mj[j])) v += NEG_BIG; }
                const size_t a = (size_t)row * ldc + c;
                if (BF16OUT) Ch[a] = f2bf(v); else Cf[a] = v;
                if (TWOUT) tp[r] = f2bf(v);
            }
            if (TWOUT) {
                // per-batch transposed: CT[(rg0>>9)*S + c*512 + (rg0&511)], 4 rows packed
                const size_t ta = ((size_t)(rg0 >> 9)) * 262144 + (size_t)c * 512 + (rg0 & 511);
                *reinterpret_cast<uint2*>(CT + ta) = *reinterpret_cast<uint2*>(tp);
            }
        }
    }
}

// ---------------------------------------------------------------------------
// fp32 -> bf16 convert for both inputs (z selects tensor)
__global__ __launch_bounds__(256)
void cvt2_f32_bf16(const float* __restrict__ a, const float* __restrict__ b,
                   ushort_t* __restrict__ oa, ushort_t* __restrict__ ob)
{
    const float* in = blockIdx.y ? b : a;
    ushort_t* out = blockIdx.y ? ob : oa;
    const long i = ((long)blockIdx.x * 256 + threadIdx.x) * 4;
    const float4 v = *reinterpret_cast<const float4*>(in + i);
    ushort_t o[4] = { f2bf(v.x), f2bf(v.y), f2bf(v.z), f2bf(v.w) };
    *reinterpret_cast<uint2*>(out + i) = *reinterpret_cast<uint2*>(o);
}

// transpose fp32 [R,C] -> bf16 [C,R]
__global__ __launch_bounds__(256)
void transpose_cvt(const float* __restrict__ in, ushort_t* __restrict__ out, int R, int C)
{
    __shared__ float t[32][33];
    const int c0 = blockIdx.x * 32, r0 = blockIdx.y * 32;
    const int tx = threadIdx.x & 31, ty = threadIdx.x >> 5;
    #pragma unroll
    for (int p = 0; p < 4; ++p)
        t[ty + p * 8][tx] = in[(size_t)(r0 + ty + p * 8) * C + c0 + tx];
    __syncthreads();
    #pragma unroll
    for (int p = 0; p < 4; ++p)
        out[(size_t)(c0 + ty + p * 8) * R + r0 + tx] = f2bf(t[tx][ty + p * 8]);
}

// one wave per row: max + 1/sum(exp)
__global__ __launch_bounds__(256)
void row_stats(const float* __restrict__ o, float* __restrict__ rmax,
               float* __restrict__ rsinv, int L)
{
    const int row  = blockIdx.x * 4 + (threadIdx.x >> 6);
    const int lane = threadIdx.x & 63;
    const float* p = o + (long)row * L;
    float m = -3.0e38f;
    for (int j = lane; j < L; j += 64) m = fmaxf(m, p[j]);
    #pragma unroll
    for (int off = 32; off > 0; off >>= 1) m = fmaxf(m, __shfl_xor(m, off));
    float s = 0.0f;
    for (int j = lane; j < L; j += 64) s += __expf(p[j] - m);
    #pragma unroll
    for (int off = 32; off > 0; off >>= 1) s += __shfl_xor(s, off);
    if (lane == 0) { rmax[row] = m; rsinv[row] = 1.0f / s; }
}

// column stats phase 1: each block scans 64 rows for 256 columns (split-K)
__global__ __launch_bounds__(256)
void col_part(const float* __restrict__ o, float* __restrict__ pm,
              float* __restrict__ ps, int L)
{
    const int b  = blockIdx.z;
    const int rc = blockIdx.y;
    const int j  = blockIdx.x * 256 + threadIdx.x;
    const float* p = o + (long)b * L * L + (long)rc * 64 * L + j;
    float m = -3.0e38f, s = 0.0f;
    #pragma unroll 4
    for (int i = 0; i < 64; ++i) {
        const float x = p[(long)i * L];
        const float mn = fmaxf(m, x);
        s = s * __expf(m - mn) + __expf(x - mn);
        m = mn;
    }
    const long idx = ((long)b * 8 + rc) * L + j;
    pm[idx] = m;
    ps[idx] = s;
}

// column stats phase 2: merge 8 partials per column
__global__ __launch_bounds__(256)
void col_combine(const float* __restrict__ pm, const float* __restrict__ ps,
                 float* __restrict__ cmax, float* __restrict__ csinv, int L)
{
    const int b = blockIdx.y;
    const int j = blockIdx.x * 256 + threadIdx.x;
    float mk[8], sk[8];
    #pragma unroll
    for (int k = 0; k < 8; ++k) {
        mk[k] = pm[((long)b * 8 + k) * L + j];
        sk[k] = ps[((long)b * 8 + k) * L + j];
    }
    float m = -3.0e38f;
    #pragma unroll
    for (int k = 0; k < 8; ++k) m = fmaxf(m, mk[k]);
    float s = 0.0f;
    #pragma unroll
    for (int k = 0; k < 8; ++k) s += sk[k] * __expf(mk[k] - m);
    cmax[b * L + j]  = m;
    csinv[b * L + j] = 1.0f / s;
}

// tiled: o1[b,i,j] = rowsm * mpos (bf16), o2T[b,j,i] = colsm * mpos (bf16)
__global__ __launch_bounds__(256)
void softmax_apply(const float* __restrict__ o,
                   ushort_t* __restrict__ o1, ushort_t* __restrict__ o2T,
                   const float* __restrict__ rmax, const float* __restrict__ rsinv,
                   const float* __restrict__ cmax, const float* __restrict__ csinv,
                   const int* __restrict__ m1, const int* __restrict__ m2)
{
    __shared__ ushort_t t[32][33];
    const int b = blockIdx.z;
    const long bo = (long)b * 512 * 512;
    const int j0 = blockIdx.x * 32, i0 = blockIdx.y * 32;
    const int tx = threadIdx.x & 31, ty = threadIdx.x >> 5;
    const int col = b * 512 + j0 + tx;
    const int mjv = m2[col];
    const float cm = cmax[col], cs = csinv[col];
    #pragma unroll
    for (int p = 0; p < 4; ++p) {
        const int i = i0 + ty + p * 8;
        const int row = b * 512 + i;
        const float x = o[bo + (long)i * 512 + j0 + tx];
        const float mp = (m1[row] != 0 && mjv != 0) ? 1.0f : 0.0f;
        o1[bo + (long)i * 512 + j0 + tx] = f2bf(__expf(x - rmax[row]) * rsinv[row] * mp);
        t[ty + p * 8][tx] = f2bf(__expf(x - cm) * cs * mp);
    }
    __syncthreads();
    #pragma unroll
    for (int p = 0; p < 4; ++p)
        o2T[bo + (long)(j0 + ty + p * 8) * 512 + i0 + tx] = t[tx][ty + p * 8];
}

// ---------------------------------------------------------------------------
extern "C" void kernel_launch(void* const* d_in, const int* in_sizes, int n_in,
                              void* d_out, int out_size, void* d_ws, size_t ws_size,
                              hipStream_t stream)
{
    const float* r1  = (const float*)d_in[0];
    const float* r2  = (const float*)d_in[1];
    const int*   m1  = (const int*)d_in[2];
    const int*   m2  = (const int*)d_in[3];
    const float* W1  = (const float*)d_in[4];
    const float* b1v = (const float*)d_in[5];
    const float* W2  = (const float*)d_in[6];
    const float* b2v = (const float*)d_in[7];
    const float* Wc1 = (const float*)d_in[8];
    const float* bc1 = (const float*)d_in[9];
    const float* Wc2 = (const float*)d_in[10];
    const float* bc2 = (const float*)d_in[11];
    float* out = (float*)d_out;

    constexpr int  Bn = 64, L = 512, D = 512;
    constexpr long CE = (long)Bn * L * D;  // 16,777,216 elements
    constexpr long S  = (long)L * L;       // 262,144
    constexpr int  NR = Bn * L;            // 32,768

    // d_out: 4 bf16 scratch slots (all dead before final fp32 writes)
    ushort_t* O    = (ushort_t*)d_out;
    ushort_t* r1b  = O;            // slot0: r1 bf16 -> later r1mT (fused epi)
    ushort_t* r2b  = O + CE;       // slot1: r2 bf16 -> later r2mT
    ushort_t* TT   = O;            // transposed base: r1mT ‖ r2mT (uniform addr)
    ushort_t* r2mT = O + CE;
    ushort_t* r1mT = O;
    ushort_t* o1b  = O + 2 * CE;   // slot2
    ushort_t* o2Tb = O + 3 * CE;   // slot3

    // workspace (byte offsets; CE bytes = 16.77 MB)
    char* wsb = (char*)d_ws;
    // R0 [0,4CE): h (2CE ushorts) -> obuf (CE floats) -> r1c‖r2c (2CE ushorts)
    ushort_t* hb   = (ushort_t*)wsb;
    float*    obuf = (float*)wsb;
    ushort_t* r1c  = (ushort_t*)wsb;
    ushort_t* r2c  = (ushort_t*)wsb + CE;
    // R1 [4CE,8CE): hc (compare hidden, 2CE ushorts)
    ushort_t* hc   = (ushort_t*)(wsb + 4 * CE);
    // R2 [8CE,12CE): r1m ‖ r2m (CE ushorts each)
    ushort_t* r1mb = (ushort_t*)(wsb + 8 * CE);
    ushort_t* r2mb = (ushort_t*)(wsb + 10 * CE);
    // R3 [12CE, ...): weights + stats
    ushort_t* W1t  = (ushort_t*)(wsb + 12 * CE);
    ushort_t* W2t  = W1t + 512 * 512;
    ushort_t* Wc1t = W2t + 512 * 512;            // [512,1024]
    ushort_t* Wc2t = Wc1t + 512 * 1024;
    float* rmaxv = (float*)(Wc2t + 512 * 512);
    float* rsinv = rmaxv + NR;
    float* cmaxv = rsinv + NR;
    float* csinv = cmaxv + NR;
    float* pmbuf = csinv + NR;                   // 8*512*64 floats
    float* psbuf = pmbuf + 8 * L * Bn;

    const dim3 blk(256);
    const dim3 gD2(D / 128, 2 * NR / 128, 1);    // combined dense: 4 x 512
    const dim3 gB(L / 128, L / 128, Bn);         // batched: 4 x 4 x 64

    // 0) convert inputs + weights
    cvt2_f32_bf16<<<dim3(CE / 1024, 2), blk, 0, stream>>>(r1, r2, r1b, r2b);
    transpose_cvt<<<dim3(16, 16), blk, 0, stream>>>(W1, W1t, 512, 512);
    transpose_cvt<<<dim3(16, 16), blk, 0, stream>>>(W2, W2t, 512, 512);
    transpose_cvt<<<dim3(16, 32), blk, 0, stream>>>(Wc1, Wc1t, 1024, 512);
    transpose_cvt<<<dim3(16, 16), blk, 0, stream>>>(Wc2, Wc2t, 512, 512);

    // 1) h = lrelu([r1;r2] @ W1 + b1)   M=65536
    gemm_nt<true,true,false,false,true,false><<<gD2, blk, 0, stream>>>(
        r1b, r1b, D, D, D, W1t, D, b1v, nullptr, nullptr, hb, D,
        nullptr, 0, 2 * NR, D, D, 0, 0, 0);
    // 2) [r1m;r2m] = lrelu(h @ W2 + b2) * mask  + fused transposed bf16 copies
    gemm_nt<true,true,true,false,true,true><<<gD2, blk, 0, stream>>>(
        hb, hb, D, D, D, W2t, D, b2v, m1, m2, r1mb, D,
        TT, NR, 2 * NR, D, D, 0, 0, 0);
    // 3) o = r1m @ r2m^T + pairmask  (batched fp32)
    gemm_nt<false,false,false,true,false,false><<<gB, blk, 0, stream>>>(
        r1mb, r1mb, D, D, D, r2mb, D, nullptr, m1, m2, obuf, L,
        nullptr, 0, L, L, D, S, S, S);
    // 4) softmax stats
    row_stats<<<dim3(NR / 4), blk, 0, stream>>>(obuf, rmaxv, rsinv, L);
    col_part<<<dim3(L / 256, 8, Bn), blk, 0, stream>>>(obuf, pmbuf, psbuf, L);
    col_combine<<<dim3(L / 256, Bn), blk, 0, stream>>>(pmbuf, psbuf, cmaxv, csinv, L);
    // 5) o1 (bf16) + o2^T (bf16)
    softmax_apply<<<dim3(16, 16, Bn), blk, 0, stream>>>(
        obuf, o1b, o2Tb, rmaxv, rsinv, cmaxv, csinv, m1, m2);
    // 6) r1_c = o1 @ r2m  (NT with r2mT)
    gemm_nt<false,false,false,false,true,false><<<gB, blk, 0, stream>>>(
        o1b, o1b, L, L, L, r2mT, L, nullptr, nullptr, nullptr, r1c, D,
        nullptr, 0, L, D, L, S, S, S);
    // 7) r2_c = o2^T @ r1m (NT with o2T, r1mT)
    gemm_nt<false,false,false,false,true,false><<<gB, blk, 0, stream>>>(
        o2Tb, o2Tb, L, L, L, r1mT, L, nullptr, nullptr, nullptr, r2c, D,
        nullptr, 0, L, D, L, S, S, S);
    // 8) hc = lrelu(cat([r1m;r2m],[r1c;r2c]) @ Wc1 + bc1)  M=65536, K=1024
    gemm_nt<true,true,false,false,true,false><<<gD2, blk, 0, stream>>>(
        r1mb, r1c, D, D, D, Wc1t, 2 * D, bc1, nullptr, nullptr, hc, D,
        nullptr, 0, 2 * NR, D, 2 * D, 0, 0, 0);
    // 9) [out1;out2] = lrelu(hc @ Wc2 + bc2) * mask  (fp32, full d_out)
    gemm_nt<true,true,true,false,false,false><<<gD2, blk, 0, stream>>>(
        hc, hc, D, D, D, Wc2t, D, bc2, m1, m2, out, D,
        nullptr, NR, 2 * NR, D, D, 0, 0, 0);
}

// Round 5
// 728.445 us; speedup vs baseline: 4.5925x; 1.0346x over previous
//
#include <hip/hip_runtime.h>

#define LRELU_SLOPE 0.01f
#define NEG_BIG -1e10f

typedef unsigned short ushort_t;
typedef __bf16 bf16x8 __attribute__((ext_vector_type(8)));
typedef float f32x4 __attribute__((ext_vector_type(4)));

static __device__ __forceinline__ float lrelu_f(float x) {
    return x >= 0.0f ? x : LRELU_SLOPE * x;
}

static __device__ __forceinline__ ushort_t f2bf(float f) {
    unsigned int u = __float_as_uint(f);
    u += 0x7fffu + ((u >> 16) & 1u);
    return (ushort_t)(u >> 16);
}

static __device__ __forceinline__ void gld_lds16(const ushort_t* g, ushort_t* l) {
    __builtin_amdgcn_global_load_lds((const __attribute__((address_space(1))) void*)g,
                                     (__attribute__((address_space(3))) void*)l,
                                     16, 0, 0);
}

// ---------------------------------------------------------------------------
// NT bf16 MFMA GEMM: C[m,n] = epi( sum_k A[m,k] * B[n,k] )
// 128x128 tile, 4 waves (2x2), BK=32, 16x16x32 MFMA.
// LDS layout XOR-swizzled: row r's k-chunk c (16B) stored at position
// c ^ ((r>>1)&3)  -> ds_read_b128 fragment reads are bank-conflict-free.
// Staging achieves this by permuting the global source chunk per lane
// (global_load_lds dest is fixed at lane*16B).
// RM mask: row < Mhalf ? rm1[row] : rm2[row-Mhalf]  (combined-M launches)
// PM mask: rm1[bz*M+row] && rm2[bz*N+col] else += NEG_BIG (batched score GEMM)
// TWOUT: also store bf16 transposed per-batch with slot swap:
//   CT[(((row>>9)+64)&127)*S + col*512 + (row&511)]  -> [r2mT | r1mT] order
// ---------------------------------------------------------------------------
template<bool BIAS, bool LRELU, bool RM, bool PM, bool BF16OUT, bool TWOUT>
__global__ __launch_bounds__(256)
void gemm_nt(const ushort_t* __restrict__ A0, const ushort_t* __restrict__ A1,
             int Ksplit, int lda0, int lda1,
             const ushort_t* __restrict__ B, int ldb,
             const float* __restrict__ bias,
             const int* __restrict__ rm1, const int* __restrict__ rm2,
             void* __restrict__ C, int ldc,
             ushort_t* __restrict__ CT, int Mhalf,
             int M, int N, int K,
             long sA, long sB, long sC)
{
    __shared__ ushort_t As[128 * 32];
    __shared__ ushort_t Bs[128 * 32];

    const int bz   = blockIdx.z;
    const int tid  = threadIdx.x;
    const int w    = tid >> 6;
    const int lane = tid & 63;
    const int wm   = w & 1;
    const int wn   = w >> 1;
    const int row0 = blockIdx.y * 128;
    const int col0 = blockIdx.x * 128;

    const ushort_t* Ab0 = A0 + (long)bz * sA;
    const ushort_t* Ab1 = A1 + (long)bz * sA;
    const ushort_t* Bb  = B  + (long)bz * sB;

    const int sRow = w * 32 + (lane >> 2);
    // swizzled source k-chunk: (lane&3) ^ ((row_local>>1)&3), row_local = lane>>2
    const int sOff = (((lane & 3) ^ ((lane >> 3) & 3)) * 8);
    ushort_t* ldsA0 = &As[w * 1024];
    ushort_t* ldsA1 = &As[w * 1024 + 512];
    ushort_t* ldsB0 = &Bs[w * 1024];
    ushort_t* ldsB1 = &Bs[w * 1024 + 512];

    const int lr = lane & 15, q = lane >> 4;
    // fragment read at swizzled chunk position q ^ ((lr>>1)&3)
    const int aBase = (wm * 64 + lr) * 32 + (q ^ ((lr >> 1) & 3)) * 8;
    const int bBase = (wn * 64 + lr) * 32 + (q ^ ((lr >> 1) & 3)) * 8;

    f32x4 acc[4][4] = {};

    for (int k0 = 0; k0 < K; k0 += 32) {
        const ushort_t* Ap; int kk, ldaP;
        if (k0 < Ksplit) { Ap = Ab0; kk = k0;          ldaP = lda0; }
        else             { Ap = Ab1; kk = k0 - Ksplit; ldaP = lda1; }

        gld_lds16(Ap + (size_t)(row0 + sRow) * ldaP + kk + sOff, ldsA0);
        gld_lds16(Ap + (size_t)(row0 + sRow + 16) * ldaP + kk + sOff, ldsA1);
        gld_lds16(Bb + (size_t)(col0 + sRow) * ldb + k0 + sOff, ldsB0);
        gld_lds16(Bb + (size_t)(col0 + sRow + 16) * ldb + k0 + sOff, ldsB1);

        __syncthreads();

        bf16x8 af[4], bf[4];
        #pragma unroll
        for (int i = 0; i < 4; ++i)
            af[i] = *reinterpret_cast<const bf16x8*>(&As[aBase + i * 16 * 32]);
        #pragma unroll
        for (int j = 0; j < 4; ++j)
            bf[j] = *reinterpret_cast<const bf16x8*>(&Bs[bBase + j * 16 * 32]);
        #pragma unroll
        for (int i = 0; i < 4; ++i)
            #pragma unroll
            for (int j = 0; j < 4; ++j)
                acc[i][j] = __builtin_amdgcn_mfma_f32_16x16x32_bf16(af[i], bf[j], acc[i][j], 0, 0, 0);

        __syncthreads();
    }

    float biasv[4];
    int mj[4];
    #pragma unroll
    for (int j = 0; j < 4; ++j) {
        const int c = col0 + wn * 64 + j * 16 + lr;
        if (BIAS) biasv[j] = bias[c];
        if (PM)   mj[j] = rm2[(long)bz * N + c];
    }
    float* Cf = (float*)C + (long)bz * sC;
    ushort_t* Ch = (ushort_t*)C + (long)bz * sC;

    #pragma unroll
    for (int i = 0; i < 4; ++i) {
        const int rg0 = row0 + wm * 64 + i * 16 + q * 4;   // first of 4 consecutive rows
        int mi4[4];
        if (RM || PM) {
            #pragma unroll
            for (int r = 0; r < 4; ++r) {
                const int row = rg0 + r;
                if (PM)      mi4[r] = rm1[(long)bz * M + row];
                else         mi4[r] = (row < Mhalf) ? rm1[row] : rm2[row - Mhalf];
            }
        }
        #pragma unroll
        for (int j = 0; j < 4; ++j) {
            const int c = col0 + wn * 64 + j * 16 + lr;
            ushort_t tp[4];
            #pragma unroll
            for (int r = 0; r < 4; ++r) {
                const int row = rg0 + r;
                float v = acc[i][j][r];
                if (BIAS) v += biasv[j];
                if (LRELU) v = lrelu_f(v);
                if (RM) v *= (float)mi4[r];
                if (PM) { if (!(mi4[r] && mj[j])) v += NEG_BIG; }
                const size_t a = (size_t)row * ldc + c;
                if (BF16OUT) Ch[a] = f2bf(v); else Cf[a] = v;
                if (TWOUT) tp[r] = f2bf(v);
            }
            if (TWOUT) {
                // slot-swapped: r1 batches -> slots 64..127, r2 batches -> 0..63
                const size_t ta = ((size_t)(((rg0 >> 9) + 64) & 127)) * 262144
                                + (size_t)c * 512 + (rg0 & 511);
                *reinterpret_cast<uint2*>(CT + ta) = *reinterpret_cast<uint2*>(tp);
            }
        }
    }
}

// ---------------------------------------------------------------------------
// fp32 -> bf16 convert for both inputs (y selects tensor)
__global__ __launch_bounds__(256)
void cvt2_f32_bf16(const float* __restrict__ a, const float* __restrict__ b,
                   ushort_t* __restrict__ oa, ushort_t* __restrict__ ob)
{
    const float* in = blockIdx.y ? b : a;
    ushort_t* out = blockIdx.y ? ob : oa;
    const long i = ((long)blockIdx.x * 256 + threadIdx.x) * 4;
    const float4 v = *reinterpret_cast<const float4*>(in + i);
    ushort_t o[4] = { f2bf(v.x), f2bf(v.y), f2bf(v.z), f2bf(v.w) };
    *reinterpret_cast<uint2*>(out + i) = *reinterpret_cast<uint2*>(o);
}

// all 4 weight transposes in one launch: fp32 [R,C] -> bf16 [C,R], z selects
__global__ __launch_bounds__(256)
void transpose_cvt4(const float* __restrict__ W1, const float* __restrict__ W2,
                    const float* __restrict__ Wc1, const float* __restrict__ Wc2,
                    ushort_t* __restrict__ W1t, ushort_t* __restrict__ W2t,
                    ushort_t* __restrict__ Wc1t, ushort_t* __restrict__ Wc2t)
{
    __shared__ float t[32][33];
    const int z = blockIdx.z;
    const float* in = (z == 0) ? W1 : (z == 1) ? W2 : (z == 2) ? Wc1 : Wc2;
    ushort_t* out   = (z == 0) ? W1t : (z == 1) ? W2t : (z == 2) ? Wc1t : Wc2t;
    const int R = (z == 2) ? 1024 : 512;
    const int C = 512;
    const int c0 = blockIdx.x * 32, r0 = blockIdx.y * 32;
    if (r0 >= R) return;
    const int tx = threadIdx.x & 31, ty = threadIdx.x >> 5;
    #pragma unroll
    for (int p = 0; p < 4; ++p)
        t[ty + p * 8][tx] = in[(size_t)(r0 + ty + p * 8) * C + c0 + tx];
    __syncthreads();
    #pragma unroll
    for (int p = 0; p < 4; ++p)
        out[(size_t)(c0 + ty + p * 8) * R + r0 + tx] = f2bf(t[tx][ty + p * 8]);
}

// one wave per row: max + 1/sum(exp)
__global__ __launch_bounds__(256)
void row_stats(const float* __restrict__ o, float* __restrict__ rmax,
               float* __restrict__ rsinv, int L)
{
    const int row  = blockIdx.x * 4 + (threadIdx.x >> 6);
    const int lane = threadIdx.x & 63;
    const float* p = o + (long)row * L;
    float m = -3.0e38f;
    for (int j = lane; j < L; j += 64) m = fmaxf(m, p[j]);
    #pragma unroll
    for (int off = 32; off > 0; off >>= 1) m = fmaxf(m, __shfl_xor(m, off));
    float s = 0.0f;
    for (int j = lane; j < L; j += 64) s += __expf(p[j] - m);
    #pragma unroll
    for (int off = 32; off > 0; off >>= 1) s += __shfl_xor(s, off);
    if (lane == 0) { rmax[row] = m; rsinv[row] = 1.0f / s; }
}

// column stats phase 1: each block scans 64 rows for 256 columns (split-K)
__global__ __launch_bounds__(256)
void col_part(const float* __restrict__ o, float* __restrict__ pm,
              float* __restrict__ ps, int L)
{
    const int b  = blockIdx.z;
    const int rc = blockIdx.y;
    const int j  = blockIdx.x * 256 + threadIdx.x;
    const float* p = o + (long)b * L * L + (long)rc * 64 * L + j;
    float m = -3.0e38f, s = 0.0f;
    #pragma unroll 4
    for (int i = 0; i < 64; ++i) {
        const float x = p[(long)i * L];
        const float mn = fmaxf(m, x);
        s = s * __expf(m - mn) + __expf(x - mn);
        m = mn;
    }
    const long idx = ((long)b * 8 + rc) * L + j;
    pm[idx] = m;
    ps[idx] = s;
}

// column stats phase 2: merge 8 partials per column
__global__ __launch_bounds__(256)
void col_combine(const float* __restrict__ pm, const float* __restrict__ ps,
                 float* __restrict__ cmax, float* __restrict__ csinv, int L)
{
    const int b = blockIdx.y;
    const int j = blockIdx.x * 256 + threadIdx.x;
    float mk[8], sk[8];
    #pragma unroll
    for (int k = 0; k < 8; ++k) {
        mk[k] = pm[((long)b * 8 + k) * L + j];
        sk[k] = ps[((long)b * 8 + k) * L + j];
    }
    float m = -3.0e38f;
    #pragma unroll
    for (int k = 0; k < 8; ++k) m = fmaxf(m, mk[k]);
    float s = 0.0f;
    #pragma unroll
    for (int k = 0; k < 8; ++k) s += sk[k] * __expf(mk[k] - m);
    cmax[b * L + j]  = m;
    csinv[b * L + j] = 1.0f / s;
}

// tiled: o1[b,i,j] = rowsm * mpos (bf16), o2T[b,j,i] = colsm * mpos (bf16)
__global__ __launch_bounds__(256)
void softmax_apply(const float* __restrict__ o,
                   ushort_t* __restrict__ o1, ushort_t* __restrict__ o2T,
                   const float* __restrict__ rmax, const float* __restrict__ rsinv,
                   const float* __restrict__ cmax, const float* __restrict__ csinv,
                   const int* __restrict__ m1, const int* __restrict__ m2)
{
    __shared__ ushort_t t[32][33];
    const int b = blockIdx.z;
    const long bo = (long)b * 512 * 512;
    const int j0 = blockIdx.x * 32, i0 = blockIdx.y * 32;
    const int tx = threadIdx.x & 31, ty = threadIdx.x >> 5;
    const int col = b * 512 + j0 + tx;
    const int mjv = m2[col];
    const float cm = cmax[col], cs = csinv[col];
    #pragma unroll
    for (int p = 0; p < 4; ++p) {
        const int i = i0 + ty + p * 8;
        const int row = b * 512 + i;
        const float x = o[bo + (long)i * 512 + j0 + tx];
        const float mp = (m1[row] != 0 && mjv != 0) ? 1.0f : 0.0f;
        o1[bo + (long)i * 512 + j0 + tx] = f2bf(__expf(x - rmax[row]) * rsinv[row] * mp);
        t[ty + p * 8][tx] = f2bf(__expf(x - cm) * cs * mp);
    }
    __syncthreads();
    #pragma unroll
    for (int p = 0; p < 4; ++p)
        o2T[bo + (long)(j0 + ty + p * 8) * 512 + i0 + tx] = t[tx][ty + p * 8];
}

// ---------------------------------------------------------------------------
extern "C" void kernel_launch(void* const* d_in, const int* in_sizes, int n_in,
                              void* d_out, int out_size, void* d_ws, size_t ws_size,
                              hipStream_t stream)
{
    const float* r1  = (const float*)d_in[0];
    const float* r2  = (const float*)d_in[1];
    const int*   m1  = (const int*)d_in[2];
    const int*   m2  = (const int*)d_in[3];
    const float* W1  = (const float*)d_in[4];
    const float* b1v = (const float*)d_in[5];
    const float* W2  = (const float*)d_in[6];
    const float* b2v = (const float*)d_in[7];
    const float* Wc1 = (const float*)d_in[8];
    const float* bc1 = (const float*)d_in[9];
    const float* Wc2 = (const float*)d_in[10];
    const float* bc2 = (const float*)d_in[11];
    float* out = (float*)d_out;

    constexpr int  Bn = 64, L = 512, D = 512;
    constexpr long CE = (long)Bn * L * D;  // 16,777,216 elements
    constexpr long S  = (long)L * L;       // 262,144
    constexpr int  NR = Bn * L;            // 32,768

    // d_out: 4 bf16 scratch slots (all dead before final fp32 writes)
    ushort_t* O    = (ushort_t*)d_out;
    ushort_t* r1b  = O;            // slot0: r1 bf16 (dead after GEMM 1)
    ushort_t* r2b  = O + CE;       // slot1: r2 bf16
    // After GEMM 2 (TWOUT slot-swapped): [slot0 | slot1] = [r2mT | r1mT],
    // uniform batch stride S from base O for the merged ctx GEMM.
    ushort_t* TT   = O;
    ushort_t* o1b  = O + 2 * CE;   // slot2: o1  (batches 0..63)
    // slot3 = o1b + CE = o2T (batches 64..127 of the same strided array)
    ushort_t* o2Tb = O + 3 * CE;

    // workspace
    char* wsb = (char*)d_ws;
    // R0 [0,4CE): h (2CE ushorts) -> obuf (CE floats) -> r1c‖r2c (2CE ushorts)
    ushort_t* hb   = (ushort_t*)wsb;
    float*    obuf = (float*)wsb;
    ushort_t* r1c  = (ushort_t*)wsb;
    // R1 [4CE,8CE): hc (compare hidden)
    ushort_t* hc   = (ushort_t*)(wsb + 4 * CE);
    // R2 [8CE,12CE): r1m ‖ r2m
    ushort_t* r1mb = (ushort_t*)(wsb + 8 * CE);
    ushort_t* r2mb = (ushort_t*)(wsb + 10 * CE);
    // R3 [12CE, ...): weights + stats
    ushort_t* W1t  = (ushort_t*)(wsb + 12 * CE);
    ushort_t* W2t  = W1t + 512 * 512;
    ushort_t* Wc1t = W2t + 512 * 512;            // [512,1024]
    ushort_t* Wc2t = Wc1t + 512 * 1024;
    float* rmaxv = (float*)(Wc2t + 512 * 512);
    float* rsinv = rmaxv + NR;
    float* cmaxv = rsinv + NR;
    float* csinv = cmaxv + NR;
    float* pmbuf = csinv + NR;                   // 8*512*64 floats
    float* psbuf = pmbuf + 8 * L * Bn;

    const dim3 blk(256);
    const dim3 gD2(D / 128, 2 * NR / 128, 1);    // combined dense: 4 x 512
    const dim3 gB(L / 128, L / 128, Bn);         // batched score: 4 x 4 x 64
    const dim3 gB2(L / 128, L / 128, 2 * Bn);    // merged ctx: 4 x 4 x 128

    // 0) convert inputs + weights
    cvt2_f32_bf16<<<dim3(CE / 1024, 2), blk, 0, stream>>>(r1, r2, r1b, r2b);
    transpose_cvt4<<<dim3(16, 32, 4), blk, 0, stream>>>(
        W1, W2, Wc1, Wc2, W1t, W2t, Wc1t, Wc2t);

    // 1) h = lrelu([r1;r2] @ W1 + b1)   M=65536
    gemm_nt<true,true,false,false,true,false><<<gD2, blk, 0, stream>>>(
        r1b, r1b, D, D, D, W1t, D, b1v, nullptr, nullptr, hb, D,
        nullptr, 0, 2 * NR, D, D, 0, 0, 0);
    // 2) [r1m;r2m] = lrelu(h @ W2 + b2) * mask  + fused transposed copies
    gemm_nt<true,true,true,false,true,true><<<gD2, blk, 0, stream>>>(
        hb, hb, D, D, D, W2t, D, b2v, m1, m2, r1mb, D,
        TT, NR, 2 * NR, D, D, 0, 0, 0);
    // 3) o = r1m @ r2m^T + pairmask  (batched fp32)
    gemm_nt<false,false,false,true,false,false><<<gB, blk, 0, stream>>>(
        r1mb, r1mb, D, D, D, r2mb, D, nullptr, m1, m2, obuf, L,
        nullptr, 0, L, L, D, S, S, S);
    // 4) softmax stats
    row_stats<<<dim3(NR / 4), blk, 0, stream>>>(obuf, rmaxv, rsinv, L);
    col_part<<<dim3(L / 256, 8, Bn), blk, 0, stream>>>(obuf, pmbuf, psbuf, L);
    col_combine<<<dim3(L / 256, Bn), blk, 0, stream>>>(pmbuf, psbuf, cmaxv, csinv, L);
    // 5) o1 (bf16) + o2^T (bf16)
    softmax_apply<<<dim3(16, 16, Bn), blk, 0, stream>>>(
        obuf, o1b, o2Tb, rmaxv, rsinv, cmaxv, csinv, m1, m2);
    // 6+7 merged) z<64: r1_c = o1 @ r2m^T-slots ; z>=64: r2_c = o2T @ r1m^T-slots
    gemm_nt<false,false,false,false,true,false><<<gB2, blk, 0, stream>>>(
        o1b, o1b, L, L, L, TT, L, nullptr, nullptr, nullptr, r1c, D,
        nullptr, 0, L, D, L, S, S, S);
    // 8) hc = lrelu(cat([r1m;r2m],[r1c;r2c]) @ Wc1 + bc1)  M=65536, K=1024
    gemm_nt<true,true,false,false,true,false><<<gD2, blk, 0, stream>>>(
        r1mb, r1c, D, D, D, Wc1t, 2 * D, bc1, nullptr, nullptr, hc, D,
        nullptr, 0, 2 * NR, D, 2 * D, 0, 0, 0);
    // 9) [out1;out2] = lrelu(hc @ Wc2 + bc2) * mask  (fp32, full d_out)
    gemm_nt<true,true,true,false,false,false><<<gD2, blk, 0, stream>>>(
        hc, hc, D, D, D, Wc2t, D, bc2, m1, m2, out, D,
        nullptr, NR, 2 * NR, D, D, 0, 0, 0);
}